// Round 13
// baseline (65.768 us; speedup 1.0000x reference)
//
#include <hip/hip_runtime.h>
#include <math.h>
#include <float.h>

#define MAX_DET 25
#define IOU_THRES 0.7f
#define MAX_WH 7680.0f
#define TOPK 256
#define MCAP 512

typedef float float4u __attribute__((ext_vector_type(4), aligned(4)));

__device__ __forceinline__ float sigm(float v) {
#pragma clang fp contract(off)
    return 1.0f / (1.0f + expf(-v));
}

// ---------------- Slim decode: 1 lane = 1 candidate ----------------
// 20 x dwordx4 (idx 4..83) + 1 scalar (idx 84) per lane, all independent and
// issued up front (max MLP). No cross-lane ops; argmax within lane over
// ascending classes (strict > keeps first max). Stores fully coalesced.
__global__ __launch_bounds__(256) void decode_all_kernel(
    const float* __restrict__ x0, const float* __restrict__ x1, const float* __restrict__ x2,
    float* __restrict__ confW, unsigned short* __restrict__ bcW)
{
#pragma clang fp contract(off)
    int g = blockIdx.x * 256 + threadIdx.x;   // candidate id, [0, 403200)
    const float* row;
    if (g < 307200)       row = x0 + (long)g * 85;
    else if (g < 384000)  row = x1 + (long)(g - 307200) * 85;
    else                  row = x2 + (long)(g - 384000) * 85;

    const float* p = row + 4;                 // idx 4 (obj), 5.. classes
    float4u v[20];
#pragma unroll
    for (int j = 0; j < 20; ++j)
        v[j] = *reinterpret_cast<const float4u*>(p + 4 * j);   // idx 4..83
    float last = row[84];                                      // class 79

    float obj = v[0][0];                      // idx 4
    float bv = -FLT_MAX; int bc = 0;
    // classes 0..78 in ascending order: v[0] elems 1..3 = classes 0..2,
    // v[j>=1] elem e = class 4j+e-1
#pragma unroll
    for (int j = 0; j < 20; ++j) {
#pragma unroll
        for (int e = 0; e < 4; ++e) {
            if (j == 0 && e == 0) continue;   // obj, not a class
            float val = v[j][e];
            int c = 4 * j + e - 1;
            if (val > bv) { bv = val; bc = c; }
        }
    }
    if (last > bv) { bv = last; bc = 79; }    // class 79

    confW[g] = sigm(bv) * sigm(obj);
    bcW[g] = (unsigned short)bc;
}

// ---------------- Fused per-group: radix-select + box recompute + NMS + gather ----------------
struct LvlParams {
    const float* feat;
    const float* x;      // level x base
    long candOff;        // candidate offset of level in confW/bcW
    long outOff;         // float offset of level in d_out
    int C;
};

template<int NY, int NX>
__device__ __forceinline__ void run_group(
    const float* __restrict__ gconf, const unsigned short* __restrict__ gbc,
    const float* __restrict__ xg, const float* __restrict__ anch,
    const float* __restrict__ feat, int C, long outOff, int b,
    float* sconf, unsigned long long* sk, unsigned* hists, float (*sbox)[4],
    int* selIdx, int* selValid, unsigned* wtot /*16*/, unsigned* misc /*4*/,
    float* __restrict__ out)
{
#pragma clang fp contract(off)
    constexpr int HW = NY * NX;
    constexpr int NPC = 3 * HW;
    const int tid = threadIdx.x;
    const int lane = tid & 63;
    const int wid = tid >> 6;

    if (tid < MAX_DET) selValid[tid] = 0;
    if (tid == 0) misc[0] = 0;
    for (int i = tid; i < 4096; i += 1024) hists[i] = 0;
    __syncthreads();

    // ---- stage conf in LDS + pass-0 histogram fused (2 sub-hists) ----
    const float4* gc4 = (const float4*)gconf;
    float4* sc4 = (float4*)sconf;
    const int sh = (tid & 1) << 11;
    for (int i = tid; i < NPC / 4; i += 1024) {
        float4 v = gc4[i];
        sc4[i] = v;
        atomicAdd(&hists[sh + (__float_as_uint(v.x) >> 19)], 1u);
        atomicAdd(&hists[sh + (__float_as_uint(v.y) >> 19)], 1u);
        atomicAdd(&hists[sh + (__float_as_uint(v.z) >> 19)], 1u);
        atomicAdd(&hists[sh + (__float_as_uint(v.w) >> 19)], 1u);
    }
    __syncthreads();

    // ---- exact top-TOPK threshold via 2-pass radix histogram ----
    unsigned B = 0, B2 = 0, K2 = 0;
    for (int pass = 0; pass < 2; ++pass) {
        if (pass == 1) {
            __syncthreads();
            for (int i = tid; i < 4096; i += 1024) hists[i] = 0;
            __syncthreads();
            for (int i = tid; i < NPC; i += 1024) {
                unsigned bits = __float_as_uint(sconf[i]);
                if ((bits >> 19) == B)
                    atomicAdd(&hists[sh + ((bits >> 8) & 2047u)], 1u);
            }
            __syncthreads();
        }
        unsigned part = hists[2 * tid] + hists[2 * tid + 1]
                      + hists[2048 + 2 * tid] + hists[2048 + 2 * tid + 1];
        unsigned s = part;
#pragma unroll
        for (int d = 1; d < 64; d <<= 1) {
            unsigned v = __shfl_down(s, d);
            if (lane < 64 - d) s += v;
        }
        if (lane == 0) wtot[wid] = s;
        __syncthreads();
        unsigned S = s;
        for (int w = wid + 1; w < 16; ++w) S += wtot[w];
        unsigned Ktgt = (pass == 0) ? TOPK : K2;
        if (S >= Ktgt && S - part < Ktgt) {     // unique crossing thread
            unsigned acc = S - part;
            for (int i = 1; i >= 0; --i) {
                int bin = 2 * tid + i;
                unsigned h = hists[bin] + hists[2048 + bin];
                acc += h;
                if (acc >= Ktgt) { misc[2] = (unsigned)bin; misc[3] = acc - h; break; }
            }
        }
        __syncthreads();
        if (pass == 0) { B = misc[2]; K2 = Ktgt - misc[3]; }
        else           { B2 = misc[2]; }
    }
    unsigned T = (B << 19) | (B2 << 8);

    // ---- collect {bits >= T} into LDS key list ----
    for (int i = tid; i < NPC; i += 1024) {
        unsigned bits = __float_as_uint(sconf[i]);
        if (bits >= T) {
            unsigned pos = atomicAdd(&misc[0], 1u);
            if (pos < MCAP)
                sk[pos] = ((unsigned long long)bits << 32) | (unsigned)(~i);
        }
    }
    __syncthreads();
    unsigned cn = misc[0];
    int n = (cn < (unsigned)MCAP) ? (int)cn : MCAP;

    // ---- recompute boxes for collected candidates (bit-identical arithmetic) ----
    for (int i = tid; i < n; i += 1024) {
        int idx = (int)(~(unsigned)sk[i]);
        const float* row = xg + (long)idx * 85;
        float v0 = row[0], v1 = row[1], v2 = row[2], v3 = row[3];
        int bc = (int)gbc[idx];
        int a   = idx / HW;
        int rem = idx - a * HW;
        int gy  = rem / NX;
        int gx  = rem - gy * NX;

        float cx = sigm(v0) * 2.0f + ((float)gx - 0.5f);
        float cy = sigm(v1) * 2.0f + ((float)gy - 0.5f);
        float tw = sigm(v2) * 2.0f, th = sigm(v3) * 2.0f;
        float w = (tw * tw) * anch[a * 2 + 0];
        float h = (th * th) * anch[a * 2 + 1];
        float x1 = cx - w / 2.0f, y1 = cy - h / 2.0f;
        float x2 = cx + w / 2.0f, y2 = cy + h / 2.0f;
        float offc = (float)bc * MAX_WH;
        sbox[i][0] = x1 + offc; sbox[i][1] = y1 + offc;
        sbox[i][2] = x2 + offc; sbox[i][3] = y2 + offc;
    }
    __syncthreads();

    // ---- wave-0 register-resident selection-sort NMS (no block barriers) ----
    if (tid < 64) {
        unsigned long long kreg[8];
#pragma unroll
        for (int j = 0; j < 8; ++j) {
            int s = tid + 64 * j;
            kreg[j] = (s < n) ? sk[s] : 0ULL;
        }
        float ex1 = 0.f, ey1 = 0.f, ex2 = 0.f, ey2 = 0.f;  // lane t holds selected box t
        int k = 0;
        while (k < MAX_DET) {
            unsigned long long mk = kreg[0]; int ms = tid;
#pragma unroll
            for (int j = 1; j < 8; ++j)
                if (kreg[j] > mk) { mk = kreg[j]; ms = tid + 64 * j; }
#pragma unroll
            for (int off = 32; off; off >>= 1) {
                unsigned long long ok = __shfl_xor(mk, off);
                int os = __shfl_xor(ms, off);
                if (ok > mk) { mk = ok; ms = os; }
            }
            if (mk == 0ULL) break;          // exhausted
#pragma unroll
            for (int j = 0; j < 8; ++j)
                if (ms == tid + 64 * j) kreg[j] = 0ULL;

            float cx1 = sbox[ms][0], cy1 = sbox[ms][1];
            float cx2 = sbox[ms][2], cy2 = sbox[ms][3];
            bool rej = false;
            if (tid < k) {
                float ltx = fmaxf(ex1, cx1), lty = fmaxf(ey1, cy1);
                float rbx = fminf(ex2, cx2), rby = fminf(ey2, cy2);
                float ww = fmaxf(rbx - ltx, 0.0f), hh = fmaxf(rby - lty, 0.0f);
                float inter = ww * hh;
                float area1 = (ex2 - ex1) * (ey2 - ey1);
                float area2 = (cx2 - cx1) * (cy2 - cy1);
                float iou = inter / (area1 + area2 - inter);
                rej = iou > IOU_THRES;
            }
            rej = __any(rej);
            if (!rej) {
                if (tid == k) { ex1 = cx1; ey1 = cy1; ex2 = cx2; ey2 = cy2; }
                if (tid == 0) { selIdx[k] = (int)(~(unsigned)mk); selValid[k] = 1; }
                ++k;
            }
        }
    }
    __syncthreads();

    // ---- fused gather: parallel over 25*C output elements ----
    const float* fb = feat + (long)b * C * HW;
    long obase = outOff + (long)b * MAX_DET * C;
    for (int e = tid; e < MAX_DET * C; e += 1024) {
        int k2 = e / C, c = e - k2 * C;
        float val = 0.0f;
        if (selValid[k2]) {
            int idx = selIdx[k2];
            int rem = idx % HW;
            val = fb[(long)c * HW + rem];   // rem = gy*NX + gx
        }
        out[obase + e] = val;
    }
}

__global__ __launch_bounds__(1024) void select_nms_gather_kernel(
    const float* __restrict__ confW, const unsigned short* __restrict__ bcW,
    const float* __restrict__ anch, float* __restrict__ out,
    LvlParams p0, LvlParams p1, LvlParams p2)
{
    __shared__ float sconf[19200];
    __shared__ unsigned long long sk[MCAP];
    __shared__ unsigned hists[4096];
    __shared__ float sbox[MCAP][4];
    __shared__ int   selIdx[MAX_DET];
    __shared__ int   selValid[MAX_DET];
    __shared__ unsigned wtot[16];
    __shared__ unsigned misc[4];

    int grp = blockIdx.x;
    int lvl = grp >> 4, b = grp & 15;
    if (lvl == 0) {
        long base = p0.candOff + (long)b * 19200;
        run_group<80, 80>(confW + base, bcW + base, p0.x + base * 85, anch + 0,
                          p0.feat, p0.C, p0.outOff, b,
                          sconf, sk, hists, sbox, selIdx, selValid, wtot, misc, out);
    } else if (lvl == 1) {
        long base = p1.candOff + (long)b * 4800;
        run_group<40, 40>(confW + base, bcW + base, p1.x + (long)b * 4800 * 85, anch + 6,
                          p1.feat, p1.C, p1.outOff, b,
                          sconf, sk, hists, sbox, selIdx, selValid, wtot, misc, out);
    } else {
        long base = p2.candOff + (long)b * 1200;
        run_group<20, 20>(confW + base, bcW + base, p2.x + (long)b * 1200 * 85, anch + 12,
                          p2.feat, p2.C, p2.outOff, b,
                          sconf, sk, hists, sbox, selIdx, selValid, wtot, misc, out);
    }
}

extern "C" void kernel_launch(void* const* d_in, const int* in_sizes, int n_in,
                              void* d_out, int out_size, void* d_ws, size_t ws_size,
                              hipStream_t stream)
{
    const float* xs[3] = {nullptr, nullptr, nullptr};
    const float* fs[3] = {nullptr, nullptr, nullptr};
    const float* anch  = nullptr;
    for (int i = 0; i < n_in; ++i) {
        const float* p = (const float*)d_in[i];
        switch (in_sizes[i]) {
            case 26112000: xs[0] = p; break;
            case 6528000:  xs[1] = p; break;
            case 1632000:  xs[2] = p; break;
            case 13107200: fs[0] = p; break;
            case 6553600:  fs[1] = p; break;
            case 3276800:  fs[2] = p; break;
            case 18:       anch  = p; break;
        }
    }

    char* wsb = (char*)d_ws;
    float*          confW = (float*)wsb;                       // 403200 f32
    unsigned short* bcW   = (unsigned short*)(wsb + 1612800L); // 403200 u16

    decode_all_kernel<<<1575, 256, 0, stream>>>(xs[0], xs[1], xs[2], confW, bcW);

    LvlParams P0{fs[0], xs[0], 0L,      0L,      128};
    LvlParams P1{fs[1], xs[1], 307200L, 51200L,  256};
    LvlParams P2{fs[2], xs[2], 384000L, 153600L, 512};

    select_nms_gather_kernel<<<48, 1024, 0, stream>>>(confW, bcW, anch, (float*)d_out, P0, P1, P2);
}

// Round 14
// 62.940 us; speedup vs baseline: 1.0449x; 1.0449x over previous
//
#include <hip/hip_runtime.h>
#include <math.h>
#include <float.h>

#define MAX_DET 25
#define IOU_THRES 0.7f
#define MAX_WH 7680.0f
#define TOPK 256
#define MCAP 512
#define CPB 64
#define STAGE_F (CPB * 85)     // 5440 floats per block
#define STAGE_F4 (STAGE_F / 4) // 1360 float4

__device__ __forceinline__ float sigm(float v) {
#pragma clang fp contract(off)
    return 1.0f / (1.0f + expf(-v));
}

// ---------------- Decode: coalesced float4 staging + conflict-free LDS compute ----------------
// Block = 256 threads, 64 candidates. Stage 21.76 KB contiguous (min line-touches),
// wave w computes partial argmax over classes [20w,20w+20) for all 64 candidates
// (LDS reads are 2-way bank-aliased = free), wave 0 combines in ascending class
// order (strict > = first-argmax, bit-identical to reference).
__global__ __launch_bounds__(256) void decode_all_kernel(
    const float* __restrict__ x0, const float* __restrict__ x1, const float* __restrict__ x2,
    float* __restrict__ confW, unsigned short* __restrict__ bcW)
{
#pragma clang fp contract(off)
    __shared__ float sx[STAGE_F];
    __shared__ float pv[4][CPB];
    __shared__ int   pc[4][CPB];

    int blk = blockIdx.x;
    const float* src; long gbase;
    if (blk < 4800)      { src = x0 + (long)blk * STAGE_F;          gbase = (long)blk * CPB; }
    else if (blk < 6000) { src = x1 + (long)(blk - 4800) * STAGE_F; gbase = 307200L + (long)(blk - 4800) * CPB; }
    else                 { src = x2 + (long)(blk - 6000) * STAGE_F; gbase = 384000L + (long)(blk - 6000) * CPB; }

    const int tid = threadIdx.x;
    const float4* s4 = (const float4*)src;
    float4* d4 = (float4*)sx;
#pragma unroll
    for (int it = 0; it < 6; ++it) {
        int i = tid + it * 256;
        if (i < STAGE_F4) d4[i] = s4[i];
    }
    __syncthreads();

    const int w = tid >> 6, c = tid & 63;
    const float* row = sx + c * 85;
    // partial argmax over this wave's 20-class block (ascending, strict >)
    float bv = -FLT_MAX; int bc = 0;
#pragma unroll
    for (int j = 0; j < 20; ++j) {
        float v = row[5 + 20 * w + j];
        if (v > bv) { bv = v; bc = 20 * w + j; }
    }
    pv[w][c] = bv; pc[w][c] = bc;
    __syncthreads();

    if (w == 0) {
        float m = pv[0][c]; int mc = pc[0][c];
#pragma unroll
        for (int ww = 1; ww < 4; ++ww) {
            float v = pv[ww][c];
            if (v > m) { m = v; mc = pc[ww][c]; }   // later waves = larger classes; strict > keeps first max
        }
        float obj = row[4];
        confW[gbase + c] = sigm(m) * sigm(obj);
        bcW[gbase + c] = (unsigned short)mc;
    }
}

// ---------------- Fused per-group: radix-select + box recompute + NMS + gather ----------------
struct LvlParams {
    const float* feat;
    const float* x;      // level x base
    long candOff;        // candidate offset of level in confW/bcW
    long outOff;         // float offset of level in d_out
    int C;
};

template<int NY, int NX>
__device__ __forceinline__ void run_group(
    const float* __restrict__ gconf, const unsigned short* __restrict__ gbc,
    const float* __restrict__ xg, const float* __restrict__ anch,
    const float* __restrict__ feat, int C, long outOff, int b,
    float* sconf, unsigned long long* sk, unsigned* hists, float (*sbox)[4],
    int* selIdx, int* selValid, unsigned* wtot /*16*/, unsigned* misc /*4*/,
    float* __restrict__ out)
{
#pragma clang fp contract(off)
    constexpr int HW = NY * NX;
    constexpr int NPC = 3 * HW;
    const int tid = threadIdx.x;
    const int lane = tid & 63;
    const int wid = tid >> 6;

    if (tid < MAX_DET) selValid[tid] = 0;
    if (tid == 0) misc[0] = 0;
    for (int i = tid; i < 4096; i += 1024) hists[i] = 0;
    __syncthreads();

    // ---- stage conf in LDS + pass-0 histogram fused (2 sub-hists) ----
    const float4* gc4 = (const float4*)gconf;
    float4* sc4 = (float4*)sconf;
    const int sh = (tid & 1) << 11;
    for (int i = tid; i < NPC / 4; i += 1024) {
        float4 v = gc4[i];
        sc4[i] = v;
        atomicAdd(&hists[sh + (__float_as_uint(v.x) >> 19)], 1u);
        atomicAdd(&hists[sh + (__float_as_uint(v.y) >> 19)], 1u);
        atomicAdd(&hists[sh + (__float_as_uint(v.z) >> 19)], 1u);
        atomicAdd(&hists[sh + (__float_as_uint(v.w) >> 19)], 1u);
    }
    __syncthreads();

    // ---- exact top-TOPK threshold via 2-pass radix histogram ----
    unsigned B = 0, B2 = 0, K2 = 0;
    for (int pass = 0; pass < 2; ++pass) {
        if (pass == 1) {
            __syncthreads();
            for (int i = tid; i < 4096; i += 1024) hists[i] = 0;
            __syncthreads();
            for (int i = tid; i < NPC; i += 1024) {
                unsigned bits = __float_as_uint(sconf[i]);
                if ((bits >> 19) == B)
                    atomicAdd(&hists[sh + ((bits >> 8) & 2047u)], 1u);
            }
            __syncthreads();
        }
        unsigned part = hists[2 * tid] + hists[2 * tid + 1]
                      + hists[2048 + 2 * tid] + hists[2048 + 2 * tid + 1];
        unsigned s = part;
#pragma unroll
        for (int d = 1; d < 64; d <<= 1) {
            unsigned v = __shfl_down(s, d);
            if (lane < 64 - d) s += v;
        }
        if (lane == 0) wtot[wid] = s;
        __syncthreads();
        unsigned S = s;
        for (int w = wid + 1; w < 16; ++w) S += wtot[w];
        unsigned Ktgt = (pass == 0) ? TOPK : K2;
        if (S >= Ktgt && S - part < Ktgt) {     // unique crossing thread
            unsigned acc = S - part;
            for (int i = 1; i >= 0; --i) {
                int bin = 2 * tid + i;
                unsigned h = hists[bin] + hists[2048 + bin];
                acc += h;
                if (acc >= Ktgt) { misc[2] = (unsigned)bin; misc[3] = acc - h; break; }
            }
        }
        __syncthreads();
        if (pass == 0) { B = misc[2]; K2 = Ktgt - misc[3]; }
        else           { B2 = misc[2]; }
    }
    unsigned T = (B << 19) | (B2 << 8);

    // ---- collect {bits >= T} into LDS key list ----
    for (int i = tid; i < NPC; i += 1024) {
        unsigned bits = __float_as_uint(sconf[i]);
        if (bits >= T) {
            unsigned pos = atomicAdd(&misc[0], 1u);
            if (pos < MCAP)
                sk[pos] = ((unsigned long long)bits << 32) | (unsigned)(~i);
        }
    }
    __syncthreads();
    unsigned cn = misc[0];
    int n = (cn < (unsigned)MCAP) ? (int)cn : MCAP;

    // ---- recompute boxes for collected candidates (bit-identical arithmetic) ----
    for (int i = tid; i < n; i += 1024) {
        int idx = (int)(~(unsigned)sk[i]);
        const float* row = xg + (long)idx * 85;
        float v0 = row[0], v1 = row[1], v2 = row[2], v3 = row[3];
        int bc = (int)gbc[idx];
        int a   = idx / HW;
        int rem = idx - a * HW;
        int gy  = rem / NX;
        int gx  = rem - gy * NX;

        float cx = sigm(v0) * 2.0f + ((float)gx - 0.5f);
        float cy = sigm(v1) * 2.0f + ((float)gy - 0.5f);
        float tw = sigm(v2) * 2.0f, th = sigm(v3) * 2.0f;
        float w = (tw * tw) * anch[a * 2 + 0];
        float h = (th * th) * anch[a * 2 + 1];
        float x1 = cx - w / 2.0f, y1 = cy - h / 2.0f;
        float x2 = cx + w / 2.0f, y2 = cy + h / 2.0f;
        float offc = (float)bc * MAX_WH;
        sbox[i][0] = x1 + offc; sbox[i][1] = y1 + offc;
        sbox[i][2] = x2 + offc; sbox[i][3] = y2 + offc;
    }
    __syncthreads();

    // ---- wave-0 register-resident selection-sort NMS (no block barriers) ----
    if (tid < 64) {
        unsigned long long kreg[8];
#pragma unroll
        for (int j = 0; j < 8; ++j) {
            int s = tid + 64 * j;
            kreg[j] = (s < n) ? sk[s] : 0ULL;
        }
        float ex1 = 0.f, ey1 = 0.f, ex2 = 0.f, ey2 = 0.f;  // lane t holds selected box t
        int k = 0;
        while (k < MAX_DET) {
            unsigned long long mk = kreg[0]; int ms = tid;
#pragma unroll
            for (int j = 1; j < 8; ++j)
                if (kreg[j] > mk) { mk = kreg[j]; ms = tid + 64 * j; }
#pragma unroll
            for (int off = 32; off; off >>= 1) {
                unsigned long long ok = __shfl_xor(mk, off);
                int os = __shfl_xor(ms, off);
                if (ok > mk) { mk = ok; ms = os; }
            }
            if (mk == 0ULL) break;          // exhausted
#pragma unroll
            for (int j = 0; j < 8; ++j)
                if (ms == tid + 64 * j) kreg[j] = 0ULL;

            float cx1 = sbox[ms][0], cy1 = sbox[ms][1];
            float cx2 = sbox[ms][2], cy2 = sbox[ms][3];
            bool rej = false;
            if (tid < k) {
                float ltx = fmaxf(ex1, cx1), lty = fmaxf(ey1, cy1);
                float rbx = fminf(ex2, cx2), rby = fminf(ey2, cy2);
                float ww = fmaxf(rbx - ltx, 0.0f), hh = fmaxf(rby - lty, 0.0f);
                float inter = ww * hh;
                float area1 = (ex2 - ex1) * (ey2 - ey1);
                float area2 = (cx2 - cx1) * (cy2 - cy1);
                float iou = inter / (area1 + area2 - inter);
                rej = iou > IOU_THRES;
            }
            rej = __any(rej);
            if (!rej) {
                if (tid == k) { ex1 = cx1; ey1 = cy1; ex2 = cx2; ey2 = cy2; }
                if (tid == 0) { selIdx[k] = (int)(~(unsigned)mk); selValid[k] = 1; }
                ++k;
            }
        }
    }
    __syncthreads();

    // ---- fused gather: parallel over 25*C output elements ----
    const float* fb = feat + (long)b * C * HW;
    long obase = outOff + (long)b * MAX_DET * C;
    for (int e = tid; e < MAX_DET * C; e += 1024) {
        int k2 = e / C, c = e - k2 * C;
        float val = 0.0f;
        if (selValid[k2]) {
            int idx = selIdx[k2];
            int rem = idx % HW;
            val = fb[(long)c * HW + rem];   // rem = gy*NX + gx
        }
        out[obase + e] = val;
    }
}

__global__ __launch_bounds__(1024) void select_nms_gather_kernel(
    const float* __restrict__ confW, const unsigned short* __restrict__ bcW,
    const float* __restrict__ anch, float* __restrict__ out,
    LvlParams p0, LvlParams p1, LvlParams p2)
{
    __shared__ float sconf[19200];
    __shared__ unsigned long long sk[MCAP];
    __shared__ unsigned hists[4096];
    __shared__ float sbox[MCAP][4];
    __shared__ int   selIdx[MAX_DET];
    __shared__ int   selValid[MAX_DET];
    __shared__ unsigned wtot[16];
    __shared__ unsigned misc[4];

    int grp = blockIdx.x;
    int lvl = grp >> 4, b = grp & 15;
    if (lvl == 0) {
        long base = p0.candOff + (long)b * 19200;
        run_group<80, 80>(confW + base, bcW + base, p0.x + base * 85, anch + 0,
                          p0.feat, p0.C, p0.outOff, b,
                          sconf, sk, hists, sbox, selIdx, selValid, wtot, misc, out);
    } else if (lvl == 1) {
        long base = p1.candOff + (long)b * 4800;
        run_group<40, 40>(confW + base, bcW + base, p1.x + (long)b * 4800 * 85, anch + 6,
                          p1.feat, p1.C, p1.outOff, b,
                          sconf, sk, hists, sbox, selIdx, selValid, wtot, misc, out);
    } else {
        long base = p2.candOff + (long)b * 1200;
        run_group<20, 20>(confW + base, bcW + base, p2.x + (long)b * 1200 * 85, anch + 12,
                          p2.feat, p2.C, p2.outOff, b,
                          sconf, sk, hists, sbox, selIdx, selValid, wtot, misc, out);
    }
}

extern "C" void kernel_launch(void* const* d_in, const int* in_sizes, int n_in,
                              void* d_out, int out_size, void* d_ws, size_t ws_size,
                              hipStream_t stream)
{
    const float* xs[3] = {nullptr, nullptr, nullptr};
    const float* fs[3] = {nullptr, nullptr, nullptr};
    const float* anch  = nullptr;
    for (int i = 0; i < n_in; ++i) {
        const float* p = (const float*)d_in[i];
        switch (in_sizes[i]) {
            case 26112000: xs[0] = p; break;
            case 6528000:  xs[1] = p; break;
            case 1632000:  xs[2] = p; break;
            case 13107200: fs[0] = p; break;
            case 6553600:  fs[1] = p; break;
            case 3276800:  fs[2] = p; break;
            case 18:       anch  = p; break;
        }
    }

    char* wsb = (char*)d_ws;
    float*          confW = (float*)wsb;                       // 403200 f32
    unsigned short* bcW   = (unsigned short*)(wsb + 1612800L); // 403200 u16

    decode_all_kernel<<<6300, 256, 0, stream>>>(xs[0], xs[1], xs[2], confW, bcW);

    LvlParams P0{fs[0], xs[0], 0L,      0L,      128};
    LvlParams P1{fs[1], xs[1], 307200L, 51200L,  256};
    LvlParams P2{fs[2], xs[2], 384000L, 153600L, 512};

    select_nms_gather_kernel<<<48, 1024, 0, stream>>>(confW, bcW, anch, (float*)d_out, P0, P1, P2);
}

// Round 15
// 61.437 us; speedup vs baseline: 1.0705x; 1.0245x over previous
//
#include <hip/hip_runtime.h>
#include <math.h>
#include <float.h>

#define MAX_DET 25
#define IOU_THRES 0.7f
#define MAX_WH 7680.0f
#define TOPK 256
#define MCAP 512
#define CPB 64
#define STAGE_F (CPB * 85)     // 5440 floats per block
#define STAGE_F4 (STAGE_F / 4) // 1360 float4 = 21*64 + 16

__device__ __forceinline__ float sigm(float v) {
#pragma clang fp contract(off)
    return 1.0f / (1.0f + expf(-v));
}

// async global->LDS 16B: per-lane global addr, wave-uniform LDS base (+lane*16 by HW)
__device__ __forceinline__ void load_lds16(const float4* g, float4* l) {
    __builtin_amdgcn_global_load_lds(
        (const __attribute__((address_space(1))) void*)(uintptr_t)(const void*)g,
        (__attribute__((address_space(3))) void*)(uintptr_t)(void*)l,
        16, 0, 0);
}

// ---------------- Decode: async global_load_lds staging + conflict-free LDS compute ----------------
__global__ __launch_bounds__(256) void decode_all_kernel(
    const float* __restrict__ x0, const float* __restrict__ x1, const float* __restrict__ x2,
    float* __restrict__ confW, unsigned short* __restrict__ bcW)
{
#pragma clang fp contract(off)
    __shared__ float sx[STAGE_F];
    __shared__ float pv[4][CPB];
    __shared__ int   pc[4][CPB];

    int blk = blockIdx.x;
    const float* src; long gbase;
    if (blk < 4800)      { src = x0 + (long)blk * STAGE_F;          gbase = (long)blk * CPB; }
    else if (blk < 6000) { src = x1 + (long)(blk - 4800) * STAGE_F; gbase = 307200L + (long)(blk - 4800) * CPB; }
    else                 { src = x2 + (long)(blk - 6000) * STAGE_F; gbase = 384000L + (long)(blk - 6000) * CPB; }

    const int tid = threadIdx.x;
    const int w = tid >> 6, lane = tid & 63;
    const float4* s4 = (const float4*)src;
    float4* sx4 = (float4*)sx;

    // 21 full wave-chunks (1 KB each) via async DMA, round-robin across 4 waves
    for (int ch = w; ch < 21; ch += 4)
        load_lds16(s4 + ch * 64 + lane, sx4 + ch * 64);
    // 16-float4 tail via normal load
    if (tid < 16) sx4[1344 + tid] = s4[1344 + tid];
    __syncthreads();   // drains vmcnt (compiler emits full waitcnt before barrier)

    const int c = tid & 63;
    const float* row = sx + c * 85;
    // wave w: partial argmax over classes [20w, 20w+20) for its candidate c
    float bv = -FLT_MAX; int bc = 0;
#pragma unroll
    for (int j = 0; j < 20; ++j) {
        float v = row[5 + 20 * w + j];
        if (v > bv) { bv = v; bc = 20 * w + j; }
    }
    pv[w][c] = bv; pc[w][c] = bc;
    __syncthreads();

    if (w == 0) {
        float m = pv[0][c]; int mc = pc[0][c];
#pragma unroll
        for (int ww = 1; ww < 4; ++ww) {
            float v = pv[ww][c];
            if (v > m) { m = v; mc = pc[ww][c]; }   // ascending blocks; strict > keeps first max
        }
        float obj = row[4];
        confW[gbase + c] = sigm(m) * sigm(obj);
        bcW[gbase + c] = (unsigned short)mc;
    }
}

// ---------------- Fused per-group: radix-select + box recompute + NMS + gather ----------------
struct LvlParams {
    const float* feat;
    const float* x;
    long candOff;
    long outOff;
    int C;
};

template<int NY, int NX>
__device__ __forceinline__ void run_group(
    const float* __restrict__ gconf, const unsigned short* __restrict__ gbc,
    const float* __restrict__ xg, const float* __restrict__ anch,
    const float* __restrict__ feat, int C, long outOff, int b,
    float* sconf, unsigned long long* sk, unsigned* hists, float (*sbox)[4],
    int* selIdx, int* selValid, unsigned* wtot /*16*/, unsigned* misc /*4*/,
    float* __restrict__ out)
{
#pragma clang fp contract(off)
    constexpr int HW = NY * NX;
    constexpr int NPC = 3 * HW;
    const int tid = threadIdx.x;
    const int lane = tid & 63;
    const int wid = tid >> 6;

    if (tid < MAX_DET) selValid[tid] = 0;
    if (tid == 0) misc[0] = 0;
    for (int i = tid; i < 4096; i += 1024) hists[i] = 0;
    __syncthreads();

    // ---- stage conf in LDS + pass-0 histogram fused (2 sub-hists) ----
    const float4* gc4 = (const float4*)gconf;
    float4* sc4 = (float4*)sconf;
    const int sh = (tid & 1) << 11;
    for (int i = tid; i < NPC / 4; i += 1024) {
        float4 v = gc4[i];
        sc4[i] = v;
        atomicAdd(&hists[sh + (__float_as_uint(v.x) >> 19)], 1u);
        atomicAdd(&hists[sh + (__float_as_uint(v.y) >> 19)], 1u);
        atomicAdd(&hists[sh + (__float_as_uint(v.z) >> 19)], 1u);
        atomicAdd(&hists[sh + (__float_as_uint(v.w) >> 19)], 1u);
    }
    __syncthreads();

    // ---- exact top-TOPK threshold via 2-pass radix histogram ----
    unsigned B = 0, B2 = 0, K2 = 0;
    for (int pass = 0; pass < 2; ++pass) {
        if (pass == 1) {
            __syncthreads();
            for (int i = tid; i < 4096; i += 1024) hists[i] = 0;
            __syncthreads();
            for (int i = tid; i < NPC; i += 1024) {
                unsigned bits = __float_as_uint(sconf[i]);
                if ((bits >> 19) == B)
                    atomicAdd(&hists[sh + ((bits >> 8) & 2047u)], 1u);
            }
            __syncthreads();
        }
        unsigned part = hists[2 * tid] + hists[2 * tid + 1]
                      + hists[2048 + 2 * tid] + hists[2048 + 2 * tid + 1];
        unsigned s = part;
#pragma unroll
        for (int d = 1; d < 64; d <<= 1) {
            unsigned v = __shfl_down(s, d);
            if (lane < 64 - d) s += v;
        }
        if (lane == 0) wtot[wid] = s;
        __syncthreads();
        unsigned S = s;
        for (int w = wid + 1; w < 16; ++w) S += wtot[w];
        unsigned Ktgt = (pass == 0) ? TOPK : K2;
        if (S >= Ktgt && S - part < Ktgt) {     // unique crossing thread
            unsigned acc = S - part;
            for (int i = 1; i >= 0; --i) {
                int bin = 2 * tid + i;
                unsigned h = hists[bin] + hists[2048 + bin];
                acc += h;
                if (acc >= Ktgt) { misc[2] = (unsigned)bin; misc[3] = acc - h; break; }
            }
        }
        __syncthreads();
        if (pass == 0) { B = misc[2]; K2 = Ktgt - misc[3]; }
        else           { B2 = misc[2]; }
    }
    unsigned T = (B << 19) | (B2 << 8);

    // ---- collect {bits >= T} into LDS key list ----
    for (int i = tid; i < NPC; i += 1024) {
        unsigned bits = __float_as_uint(sconf[i]);
        if (bits >= T) {
            unsigned pos = atomicAdd(&misc[0], 1u);
            if (pos < MCAP)
                sk[pos] = ((unsigned long long)bits << 32) | (unsigned)(~i);
        }
    }
    __syncthreads();
    unsigned cn = misc[0];
    int n = (cn < (unsigned)MCAP) ? (int)cn : MCAP;

    // ---- recompute boxes for collected candidates (bit-identical arithmetic) ----
    for (int i = tid; i < n; i += 1024) {
        int idx = (int)(~(unsigned)sk[i]);
        const float* row = xg + (long)idx * 85;
        float v0 = row[0], v1 = row[1], v2 = row[2], v3 = row[3];
        int bc = (int)gbc[idx];
        int a   = idx / HW;
        int rem = idx - a * HW;
        int gy  = rem / NX;
        int gx  = rem - gy * NX;

        float cx = sigm(v0) * 2.0f + ((float)gx - 0.5f);
        float cy = sigm(v1) * 2.0f + ((float)gy - 0.5f);
        float tw = sigm(v2) * 2.0f, th = sigm(v3) * 2.0f;
        float w = (tw * tw) * anch[a * 2 + 0];
        float h = (th * th) * anch[a * 2 + 1];
        float x1 = cx - w / 2.0f, y1 = cy - h / 2.0f;
        float x2 = cx + w / 2.0f, y2 = cy + h / 2.0f;
        float offc = (float)bc * MAX_WH;
        sbox[i][0] = x1 + offc; sbox[i][1] = y1 + offc;
        sbox[i][2] = x2 + offc; sbox[i][3] = y2 + offc;
    }
    __syncthreads();

    // ---- wave-0 register-resident selection-sort NMS (no block barriers) ----
    if (tid < 64) {
        unsigned long long kreg[8];
#pragma unroll
        for (int j = 0; j < 8; ++j) {
            int s = tid + 64 * j;
            kreg[j] = (s < n) ? sk[s] : 0ULL;
        }
        float ex1 = 0.f, ey1 = 0.f, ex2 = 0.f, ey2 = 0.f;  // lane t holds selected box t
        int k = 0;
        while (k < MAX_DET) {
            unsigned long long mk = kreg[0]; int ms = tid;
#pragma unroll
            for (int j = 1; j < 8; ++j)
                if (kreg[j] > mk) { mk = kreg[j]; ms = tid + 64 * j; }
#pragma unroll
            for (int off = 32; off; off >>= 1) {
                unsigned long long ok = __shfl_xor(mk, off);
                int os = __shfl_xor(ms, off);
                if (ok > mk) { mk = ok; ms = os; }
            }
            if (mk == 0ULL) break;          // exhausted
#pragma unroll
            for (int j = 0; j < 8; ++j)
                if (ms == tid + 64 * j) kreg[j] = 0ULL;

            float cx1 = sbox[ms][0], cy1 = sbox[ms][1];
            float cx2 = sbox[ms][2], cy2 = sbox[ms][3];
            bool rej = false;
            if (tid < k) {
                float ltx = fmaxf(ex1, cx1), lty = fmaxf(ey1, cy1);
                float rbx = fminf(ex2, cx2), rby = fminf(ey2, cy2);
                float ww = fmaxf(rbx - ltx, 0.0f), hh = fmaxf(rby - lty, 0.0f);
                float inter = ww * hh;
                float area1 = (ex2 - ex1) * (ey2 - ey1);
                float area2 = (cx2 - cx1) * (cy2 - cy1);
                float iou = inter / (area1 + area2 - inter);
                rej = iou > IOU_THRES;
            }
            rej = __any(rej);
            if (!rej) {
                if (tid == k) { ex1 = cx1; ey1 = cy1; ex2 = cx2; ey2 = cy2; }
                if (tid == 0) { selIdx[k] = (int)(~(unsigned)mk); selValid[k] = 1; }
                ++k;
            }
        }
    }
    __syncthreads();

    // ---- fused gather: parallel over 25*C output elements ----
    const float* fb = feat + (long)b * C * HW;
    long obase = outOff + (long)b * MAX_DET * C;
    for (int e = tid; e < MAX_DET * C; e += 1024) {
        int k2 = e / C, c = e - k2 * C;
        float val = 0.0f;
        if (selValid[k2]) {
            int idx = selIdx[k2];
            int rem = idx % HW;
            val = fb[(long)c * HW + rem];   // rem = gy*NX + gx
        }
        out[obase + e] = val;
    }
}

__global__ __launch_bounds__(1024) void select_nms_gather_kernel(
    const float* __restrict__ confW, const unsigned short* __restrict__ bcW,
    const float* __restrict__ anch, float* __restrict__ out,
    LvlParams p0, LvlParams p1, LvlParams p2)
{
    __shared__ float sconf[19200];
    __shared__ unsigned long long sk[MCAP];
    __shared__ unsigned hists[4096];
    __shared__ float sbox[MCAP][4];
    __shared__ int   selIdx[MAX_DET];
    __shared__ int   selValid[MAX_DET];
    __shared__ unsigned wtot[16];
    __shared__ unsigned misc[4];

    int grp = blockIdx.x;
    int lvl = grp >> 4, b = grp & 15;
    if (lvl == 0) {
        long base = p0.candOff + (long)b * 19200;
        run_group<80, 80>(confW + base, bcW + base, p0.x + base * 85, anch + 0,
                          p0.feat, p0.C, p0.outOff, b,
                          sconf, sk, hists, sbox, selIdx, selValid, wtot, misc, out);
    } else if (lvl == 1) {
        long base = p1.candOff + (long)b * 4800;
        run_group<40, 40>(confW + base, bcW + base, p1.x + (long)b * 4800 * 85, anch + 6,
                          p1.feat, p1.C, p1.outOff, b,
                          sconf, sk, hists, sbox, selIdx, selValid, wtot, misc, out);
    } else {
        long base = p2.candOff + (long)b * 1200;
        run_group<20, 20>(confW + base, bcW + base, p2.x + (long)b * 1200 * 85, anch + 12,
                          p2.feat, p2.C, p2.outOff, b,
                          sconf, sk, hists, sbox, selIdx, selValid, wtot, misc, out);
    }
}

extern "C" void kernel_launch(void* const* d_in, const int* in_sizes, int n_in,
                              void* d_out, int out_size, void* d_ws, size_t ws_size,
                              hipStream_t stream)
{
    const float* xs[3] = {nullptr, nullptr, nullptr};
    const float* fs[3] = {nullptr, nullptr, nullptr};
    const float* anch  = nullptr;
    for (int i = 0; i < n_in; ++i) {
        const float* p = (const float*)d_in[i];
        switch (in_sizes[i]) {
            case 26112000: xs[0] = p; break;
            case 6528000:  xs[1] = p; break;
            case 1632000:  xs[2] = p; break;
            case 13107200: fs[0] = p; break;
            case 6553600:  fs[1] = p; break;
            case 3276800:  fs[2] = p; break;
            case 18:       anch  = p; break;
        }
    }

    char* wsb = (char*)d_ws;
    float*          confW = (float*)wsb;                       // 403200 f32
    unsigned short* bcW   = (unsigned short*)(wsb + 1612800L); // 403200 u16

    decode_all_kernel<<<6300, 256, 0, stream>>>(xs[0], xs[1], xs[2], confW, bcW);

    LvlParams P0{fs[0], xs[0], 0L,      0L,      128};
    LvlParams P1{fs[1], xs[1], 307200L, 51200L,  256};
    LvlParams P2{fs[2], xs[2], 384000L, 153600L, 512};

    select_nms_gather_kernel<<<48, 1024, 0, stream>>>(confW, bcW, anch, (float*)d_out, P0, P1, P2);
}